// Round 5
// baseline (363.176 us; speedup 1.0000x reference)
//
#include <hip/hip_runtime.h>
#include <math.h>

#define BB 8
#define CIN 256
#define HW 4096
#define BHW 32768          // B*HW
#define COUT 256
#define KTOT 2304          // CIN*9
#define WS_N (BB*9*HW)     // 294912 floats per param array

// ws layout (floats):
//   0        sy   [WS_N]
//   WS_N     sx   [WS_N]
//   2*WS_N   m    [WS_N]
//   3*WS_N   w16  [294912 floats = 589824 bf16]  (K order: (cblk*9+kk)*32+cin)
#define WOFF2_OFF (4*WS_N)            // woff2 [256*9*28]
#define ACC_OFF   (WOFF2_OFF + 64512) // accum [27][BHW]
#define ATOMIC_NEED ((size_t)(ACC_OFF + 27*BHW) * 4)

typedef __bf16 bf16;
typedef __attribute__((ext_vector_type(8))) __bf16 bf16x8;
typedef __attribute__((ext_vector_type(4))) __bf16 bf16x4;
typedef __attribute__((ext_vector_type(4))) float f32x4;
struct __attribute__((packed, aligned(4))) f2x { float x, y; };

// ---------------- wprep: w_off [27][256*9] -> woff2 [(c*9+t)*28 + j] ----------------
__global__ __launch_bounds__(256) void wprep_kernel(
    const float* __restrict__ w_off, float* __restrict__ woff2)
{
  const int c = blockIdx.x;
  const int tid = threadIdx.x;
  if (tid < 252) {
    int t = tid / 28, j = tid % 28;
    float v = (j < 27) ? w_off[(size_t)j * KTOT + c * 9 + t] : 0.f;
    woff2[((size_t)c * 9 + t) * 28 + j] = v;
  }
}

// ---------------- offconv: NS-way c-split, atomicAdd accumulate ----------------
template<int NS>
__global__ __launch_bounds__(256) void offconv_atom_kernel(
    const float* __restrict__ x, const float* __restrict__ woff2,
    float* __restrict__ accum)
{
  const int tid = threadIdx.x;
  const int bs  = blockIdx.x;
  const int st  = bs & 15;
  const int b   = (bs >> 4) & 7;
  const int s   = bs >> 7;                  // 0..NS-1
  const int pos = st * 256 + tid;
  const int ho  = pos >> 6, wo = pos & 63;
  const int c0  = s * (CIN / NS), c1 = c0 + CIN / NS;

  int   toff[9];
  float tvf[9];
#pragma unroll
  for (int t = 0; t < 9; ++t) {
    int ky = t / 3, kx = t % 3;
    int yy = ho - 1 + ky, xx = wo - 1 + kx;
    bool ok = ((unsigned)yy < 64u) && ((unsigned)xx < 64u);
    toff[t] = (min(max(yy, 0), 63)) * 64 + min(max(xx, 0), 63);
    tvf[t]  = ok ? 1.f : 0.f;
  }

  float a[27];
#pragma unroll
  for (int j = 0; j < 27; ++j) a[j] = 0.f;

  const float* xb = x + (size_t)b * CIN * HW;
#pragma unroll 2
  for (int c = c0; c < c1; ++c) {
    const float* xc = xb + (size_t)c * HW;
    float xv[9];
#pragma unroll
    for (int t = 0; t < 9; ++t) xv[t] = xc[toff[t]] * tvf[t];
    const float4* wr4 = (const float4*)(woff2 + (size_t)c * 252);
#pragma unroll
    for (int t = 0; t < 9; ++t) {
      float4 wb[7];
#pragma unroll
      for (int q = 0; q < 7; ++q) wb[q] = wr4[t * 7 + q];
#pragma unroll
      for (int q = 0; q < 7; ++q) {
        int j0 = q * 4;
        a[j0 + 0] = fmaf(wb[q].x, xv[t], a[j0 + 0]);
        a[j0 + 1] = fmaf(wb[q].y, xv[t], a[j0 + 1]);
        a[j0 + 2] = fmaf(wb[q].z, xv[t], a[j0 + 2]);
        if (j0 + 3 < 27) a[j0 + 3] = fmaf(wb[q].w, xv[t], a[j0 + 3]);
      }
    }
  }

  const int bp = b * HW + pos;
#pragma unroll
  for (int j = 0; j < 27; ++j)
    atomicAdd(&accum[(size_t)j * BHW + bp], a[j]);
}

// fallback (no accum buffer): NS=1 direct write
__global__ __launch_bounds__(256) void offconv_direct_kernel(
    const float* __restrict__ x, const float* __restrict__ woff2,
    const float* __restrict__ b_off, float* __restrict__ ws)
{
  const int tid = threadIdx.x;
  const int bs  = blockIdx.x;
  const int st  = bs & 15;
  const int b   = bs >> 4;
  const int pos = st * 256 + tid;
  const int ho  = pos >> 6, wo = pos & 63;

  int   toff[9];
  float tvf[9];
#pragma unroll
  for (int t = 0; t < 9; ++t) {
    int ky = t / 3, kx = t % 3;
    int yy = ho - 1 + ky, xx = wo - 1 + kx;
    bool ok = ((unsigned)yy < 64u) && ((unsigned)xx < 64u);
    toff[t] = (min(max(yy, 0), 63)) * 64 + min(max(xx, 0), 63);
    tvf[t]  = ok ? 1.f : 0.f;
  }
  float a[27];
#pragma unroll
  for (int j = 0; j < 27; ++j) a[j] = 0.f;
  const float* xb = x + (size_t)b * CIN * HW;
#pragma unroll 2
  for (int c = 0; c < CIN; ++c) {
    const float* xc = xb + (size_t)c * HW;
    float xv[9];
#pragma unroll
    for (int t = 0; t < 9; ++t) xv[t] = xc[toff[t]] * tvf[t];
    const float4* wr4 = (const float4*)(woff2 + (size_t)c * 252);
#pragma unroll
    for (int t = 0; t < 9; ++t) {
      float4 wb[7];
#pragma unroll
      for (int q = 0; q < 7; ++q) wb[q] = wr4[t * 7 + q];
#pragma unroll
      for (int q = 0; q < 7; ++q) {
        int j0 = q * 4;
        a[j0 + 0] = fmaf(wb[q].x, xv[t], a[j0 + 0]);
        a[j0 + 1] = fmaf(wb[q].y, xv[t], a[j0 + 1]);
        a[j0 + 2] = fmaf(wb[q].z, xv[t], a[j0 + 2]);
        if (j0 + 3 < 27) a[j0 + 3] = fmaf(wb[q].w, xv[t], a[j0 + 3]);
      }
    }
  }
#pragma unroll
  for (int kk = 0; kk < 9; ++kk) {
    float syv = a[2 * kk]     + b_off[2 * kk]     + (float)(ho - 1 + kk / 3);
    float sxv = a[2 * kk + 1] + b_off[2 * kk + 1] + (float)(wo - 1 + kk % 3);
    float mv  = a[18 + kk]    + b_off[18 + kk];
    ws[(b * 9 + kk) * HW + pos]            = syv;
    ws[WS_N + (b * 9 + kk) * HW + pos]     = sxv;
    ws[2 * WS_N + (b * 9 + kk) * HW + pos] = 1.f / (1.f + expf(-mv));
  }
}

// ---------------- combine: accum + bias -> sy/sx/m ----------------
__global__ __launch_bounds__(256) void combine_kernel(
    const float* __restrict__ b_off, float* __restrict__ ws)
{
  int gid = blockIdx.x * 256 + threadIdx.x;   // 9*BHW total
  int kk = gid >> 15, bp = gid & 32767;
  int b = bp >> 12, pos = bp & 4095;
  int ho = pos >> 6, wo = pos & 63;
  const float* acc = ws + ACC_OFF;
  int jy = 2 * kk, jx = 2 * kk + 1, jm = 18 + kk;
  float syv = acc[(size_t)jy * BHW + bp] + b_off[jy] + (float)(ho - 1 + kk / 3);
  float sxv = acc[(size_t)jx * BHW + bp] + b_off[jx] + (float)(wo - 1 + kk % 3);
  float mv  = acc[(size_t)jm * BHW + bp] + b_off[jm];
  ws[(b * 9 + kk) * HW + pos]            = syv;
  ws[WS_N + (b * 9 + kk) * HW + pos]     = sxv;
  ws[2 * WS_N + (b * 9 + kk) * HW + pos] = 1.f / (1.f + expf(-mv));
}

// ---------------- wconv: w_dcn -> bf16, K reorder (cblk*9+kk)*32+cin ----------------
__global__ __launch_bounds__(256) void wconv_kernel(
    const float* __restrict__ w, bf16* __restrict__ o)
{
  const int co = blockIdx.x;
  const int c  = threadIdx.x;
  const int cblk = c >> 5, cin = c & 31;
#pragma unroll
  for (int kk = 0; kk < 9; ++kk)
    o[(size_t)co * KTOT + (cblk * 9 + kk) * 32 + cin] = (bf16)w[(size_t)co * KTOT + c * 9 + kk];
}

// ---------------- dcn: bilinear gather + MFMA GEMM ----------------
// K order: step s = cblk*9 + kk handles channels cblk*32..+31, tap kk.
// 512 thr (8 waves), tile 256co x 64pos. LDS double-buffered, one raw barrier/iter.
// Global prefetch issued at iter i for step i+2, consumed at iter i+1 (crosses barrier).
#define KSTEP 32
#define NK 72
#define AP 36
#define ASZ (256*AP)
#define BSZ (64*AP)

__global__ __launch_bounds__(512, 4) void dcn_mfma3_kernel(
    const float* __restrict__ x, const bf16* __restrict__ w16,
    const float* __restrict__ b_dcn, const float* __restrict__ ws,
    float* __restrict__ out)
{
  __shared__ bf16 A_lds[2 * ASZ];      // 36.9 KB
  __shared__ bf16 B_lds[2 * BSZ];      // 9.2 KB
  __shared__ int   poff0[576], poff1[576];
  __shared__ float pa0s[576], pa1s[576], pw0s[576], pw1s[576];   // 13.8 KB

  const int tid  = threadIdx.x;
  const int b    = blockIdx.x & 7;      // batch -> XCD (round-robin dispatch)
  const int pos0 = (blockIdx.x >> 3) * 64;

  for (int t = tid; t < 576; t += 512) {
    int kk = t >> 6, p = t & 63;
    int pos = pos0 + p;
    float sy = ws[(b * 9 + kk) * HW + pos];
    float sx = ws[WS_N + (b * 9 + kk) * HW + pos];
    float m  = ws[2 * WS_N + (b * 9 + kk) * HW + pos];
    float y0f = floorf(sy), x0f = floorf(sx);
    int y0 = (int)y0f, x0 = (int)x0f;
    float wy = sy - y0f, wx = sx - x0f;
    int ix0 = min(max(x0, 0), 63), ix1 = min(max(x0 + 1, 0), 63);
    int bx  = min(max(x0, 0), 62);
    float vx0 = (x0 >= 0  && x0 <= 63) ? 1.f : 0.f;
    float vx1 = (x0 >= -1 && x0 <= 62) ? 1.f : 0.f;
    float wx0 = (1.f - wx) * vx0, wx1 = wx * vx1;
    float a0 = (ix0 == bx     ? wx0 : 0.f) + (ix1 == bx     ? wx1 : 0.f);
    float a1 = (ix0 == bx + 1 ? wx0 : 0.f) + (ix1 == bx + 1 ? wx1 : 0.f);
    int rb0 = min(max(y0, 0), 63), rb1 = min(max(y0 + 1, 0), 63);
    float vy0 = (y0 >= 0  && y0 <= 63) ? 1.f : 0.f;
    float vy1 = (y0 >= -1 && y0 <= 62) ? 1.f : 0.f;
    poff0[t] = rb0 * 64 + bx;
    poff1[t] = rb1 * 64 + bx;
    pa0s[t] = a0; pa1s[t] = a1;
    pw0s[t] = (1.f - wy) * vy0 * m;
    pw1s[t] = wy * vy1 * m;
  }
  __syncthreads();

  const int lane = tid & 63, wid = tid >> 6;
  const int wr = wid >> 1, wc = wid & 1;
  const int lm = lane & 15, lk = lane >> 4;
  const int aco = tid & 255, ah = tid >> 8;
  const int gp = tid & 63, gg = tid >> 6;

  f32x4 acc[4][2];
#pragma unroll
  for (int a = 0; a < 4; ++a)
#pragma unroll
    for (int c = 0; c < 2; ++c)
      acc[a][c] = (f32x4){0.f, 0.f, 0.f, 0.f};

  const float* xb = x + (size_t)b * CIN * HW;
  const bf16* wrowa = w16 + (size_t)aco * KTOT + ah * 16;
  const int aoff = aco * AP + ah * 16;
  const int boff = gp * AP + gg * 4;

  uint4 ar0, ar1;
  f2x r0[4], r1[4];
  int o0, o1;

  // ---- prologue: step 0 load, combine, write buf0; issue step-1 loads
  o0 = poff0[gp]; o1 = poff1[gp];
  ar0 = *(const uint4*)(wrowa);
  ar1 = *(const uint4*)(wrowa + 8);
  {
    const float* pc = xb + (size_t)(gg * 4) * HW;
#pragma unroll
    for (int e = 0; e < 4; ++e) {
      r0[e] = *(const f2x*)(pc + o0);
      r1[e] = *(const f2x*)(pc + o1);
      pc += HW;
    }
  }
  {
    float pa0 = pa0s[gp], pa1 = pa1s[gp], pw0 = pw0s[gp], pw1 = pw1s[gp];
    bf16x4 vv;
#pragma unroll
    for (int e = 0; e < 4; ++e) {
      float v = pw0 * fmaf(pa0, r0[e].x, pa1 * r0[e].y)
              + pw1 * fmaf(pa0, r1[e].x, pa1 * r1[e].y);
      vv[e] = (bf16)v;
    }
    *(uint4*)&A_lds[aoff]     = ar0;
    *(uint4*)&A_lds[aoff + 8] = ar1;
    *(bf16x4*)&B_lds[boff]    = vv;
  }
  // issue step 1 (tap 1, cblk 0)
  o0 = poff0[64 + gp]; o1 = poff1[64 + gp];
  ar0 = *(const uint4*)(wrowa + 32);
  ar1 = *(const uint4*)(wrowa + 40);
  {
    const float* pc = xb + (size_t)(gg * 4) * HW;
#pragma unroll
    for (int e = 0; e < 4; ++e) {
      r0[e] = *(const f2x*)(pc + o0);
      r1[e] = *(const f2x*)(pc + o1);
      pc += HW;
    }
  }
  asm volatile("s_waitcnt lgkmcnt(0)" ::: "memory");
  __builtin_amdgcn_s_barrier();

  // ---- main loop: iters i=0..NK-2
  int t1 = 1, t2 = 2, cb2 = 0;
  for (int i = 0; i < NK - 1; ++i) {
    const int ri = i & 1;
    bf16* RDA = A_lds + ri * ASZ;
    bf16* RDB = B_lds + ri * BSZ;
    bf16* WRA = A_lds + (ri ^ 1) * ASZ;
    bf16* WRB = B_lds + (ri ^ 1) * BSZ;

    // combine step i+1 (regs loaded last iter), write to WR
    {
      int pb = t1 * 64 + gp;
      float pa0 = pa0s[pb], pa1 = pa1s[pb], pw0 = pw0s[pb], pw1 = pw1s[pb];
      bf16x4 vv;
#pragma unroll
      for (int e = 0; e < 4; ++e) {
        float v = pw0 * fmaf(pa0, r0[e].x, pa1 * r0[e].y)
                + pw1 * fmaf(pa0, r1[e].x, pa1 * r1[e].y);
        vv[e] = (bf16)v;
      }
      *(uint4*)&WRA[aoff]     = ar0;
      *(uint4*)&WRA[aoff + 8] = ar1;
      *(bf16x4*)&WRB[boff]    = vv;
    }
    // issue loads for step i+2 (clamped to NK-1)
    {
      int pb2 = t2 * 64 + gp;
      o0 = poff0[pb2]; o1 = poff1[pb2];
      int ks = (i + 2 <= NK - 1) ? i + 2 : NK - 1;
      ar0 = *(const uint4*)(wrowa + ks * KSTEP);
      ar1 = *(const uint4*)(wrowa + ks * KSTEP + 8);
      const float* pc = xb + (size_t)(cb2 + gg * 4) * HW;
#pragma unroll
      for (int e = 0; e < 4; ++e) {
        r0[e] = *(const f2x*)(pc + o0);
        r1[e] = *(const f2x*)(pc + o1);
        pc += HW;
      }
    }
    // fragments (step i) + MFMA
    {
      bf16x8 af0 = *(const bf16x8*)&RDA[(wr * 64 +  0 + lm) * AP + lk * 8];
      bf16x8 af1 = *(const bf16x8*)&RDA[(wr * 64 + 16 + lm) * AP + lk * 8];
      bf16x8 af2 = *(const bf16x8*)&RDA[(wr * 64 + 32 + lm) * AP + lk * 8];
      bf16x8 af3 = *(const bf16x8*)&RDA[(wr * 64 + 48 + lm) * AP + lk * 8];
      bf16x8 bf0 = *(const bf16x8*)&RDB[(wc * 32 +  0 + lm) * AP + lk * 8];
      bf16x8 bf1 = *(const bf16x8*)&RDB[(wc * 32 + 16 + lm) * AP + lk * 8];
      acc[0][0] = __builtin_amdgcn_mfma_f32_16x16x32_bf16(af0, bf0, acc[0][0], 0, 0, 0);
      acc[0][1] = __builtin_amdgcn_mfma_f32_16x16x32_bf16(af0, bf1, acc[0][1], 0, 0, 0);
      acc[1][0] = __builtin_amdgcn_mfma_f32_16x16x32_bf16(af1, bf0, acc[1][0], 0, 0, 0);
      acc[1][1] = __builtin_amdgcn_mfma_f32_16x16x32_bf16(af1, bf1, acc[1][1], 0, 0, 0);
      acc[2][0] = __builtin_amdgcn_mfma_f32_16x16x32_bf16(af2, bf0, acc[2][0], 0, 0, 0);
      acc[2][1] = __builtin_amdgcn_mfma_f32_16x16x32_bf16(af2, bf1, acc[2][1], 0, 0, 0);
      acc[3][0] = __builtin_amdgcn_mfma_f32_16x16x32_bf16(af3, bf0, acc[3][0], 0, 0, 0);
      acc[3][1] = __builtin_amdgcn_mfma_f32_16x16x32_bf16(af3, bf1, acc[3][1], 0, 0, 0);
    }
    asm volatile("s_waitcnt lgkmcnt(0)" ::: "memory");
    __builtin_amdgcn_s_barrier();

    ++t1; if (t1 == 9) t1 = 0;
    ++t2; if (t2 == 9) { t2 = 0; cb2 += 32; }
    if (cb2 == 256) { cb2 = 224; t2 = 8; }
  }

  // ---- final step NK-1 from buf[(NK-1)&1]
  {
    bf16* RDA = A_lds + ((NK - 1) & 1) * ASZ;
    bf16* RDB = B_lds + ((NK - 1) & 1) * BSZ;
    bf16x8 af0 = *(const bf16x8*)&RDA[(wr * 64 +  0 + lm) * AP + lk * 8];
    bf16x8 af1 = *(const bf16x8*)&RDA[(wr * 64 + 16 + lm) * AP + lk * 8];
    bf16x8 af2 = *(const bf16x8*)&RDA[(wr * 64 + 32 + lm) * AP + lk * 8];
    bf16x8 af3 = *(const bf16x8*)&RDA[(wr * 64 + 48 + lm) * AP + lk * 8];
    bf16x8 bf0 = *(const bf16x8*)&RDB[(wc * 32 +  0 + lm) * AP + lk * 8];
    bf16x8 bf1 = *(const bf16x8*)&RDB[(wc * 32 + 16 + lm) * AP + lk * 8];
    acc[0][0] = __builtin_amdgcn_mfma_f32_16x16x32_bf16(af0, bf0, acc[0][0], 0, 0, 0);
    acc[0][1] = __builtin_amdgcn_mfma_f32_16x16x32_bf16(af0, bf1, acc[0][1], 0, 0, 0);
    acc[1][0] = __builtin_amdgcn_mfma_f32_16x16x32_bf16(af1, bf0, acc[1][0], 0, 0, 0);
    acc[1][1] = __builtin_amdgcn_mfma_f32_16x16x32_bf16(af1, bf1, acc[1][1], 0, 0, 0);
    acc[2][0] = __builtin_amdgcn_mfma_f32_16x16x32_bf16(af2, bf0, acc[2][0], 0, 0, 0);
    acc[2][1] = __builtin_amdgcn_mfma_f32_16x16x32_bf16(af2, bf1, acc[2][1], 0, 0, 0);
    acc[3][0] = __builtin_amdgcn_mfma_f32_16x16x32_bf16(af3, bf0, acc[3][0], 0, 0, 0);
    acc[3][1] = __builtin_amdgcn_mfma_f32_16x16x32_bf16(af3, bf1, acc[3][1], 0, 0, 0);
  }

  // ---- epilogue: bias + store (C/D: col=lane&15, row=(lane>>4)*4+reg)
  const int pbase = pos0 + wc * 32;
#pragma unroll
  for (int fr = 0; fr < 4; ++fr) {
#pragma unroll
    for (int r = 0; r < 4; ++r) {
      int co = wr * 64 + fr * 16 + lk * 4 + r;
      float bias = b_dcn[co];
      float* orow = out + ((size_t)b * COUT + co) * HW + pbase;
      orow[lm]      = acc[fr][0][r] + bias;
      orow[16 + lm] = acc[fr][1][r] + bias;
    }
  }
}

extern "C" void kernel_launch(void* const* d_in, const int* in_sizes, int n_in,
                              void* d_out, int out_size, void* d_ws, size_t ws_size,
                              hipStream_t stream) {
  const float* x     = (const float*)d_in[0];
  const float* w_off = (const float*)d_in[1];
  const float* b_off = (const float*)d_in[2];
  const float* w_dcn = (const float*)d_in[3];
  const float* b_dcn = (const float*)d_in[4];
  float* out = (float*)d_out;
  float* ws  = (float*)d_ws;
  bf16* w16  = (bf16*)(ws + 3 * WS_N);
  float* woff2 = ws + WOFF2_OFF;

  wprep_kernel<<<256, 256, 0, stream>>>(w_off, woff2);
  if (ws_size >= ATOMIC_NEED) {
    hipMemsetAsync(ws + ACC_OFF, 0, (size_t)27 * BHW * 4, stream);
    offconv_atom_kernel<8><<<8 * BB * 16, 256, 0, stream>>>(x, woff2, ws + ACC_OFF);
    combine_kernel<<<(9 * BHW) / 256, 256, 0, stream>>>(b_off, ws);
  } else {
    offconv_direct_kernel<<<BB * 16, 256, 0, stream>>>(x, woff2, b_off, ws);
  }
  wconv_kernel<<<COUT, 256, 0, stream>>>(w_dcn, w16);
  dcn_mfma3_kernel<<<BB * (HW / 64), 512, 0, stream>>>(x, w16, b_dcn, ws, out);
}

// Round 6
// 251.908 us; speedup vs baseline: 1.4417x; 1.4417x over previous
//
#include <hip/hip_runtime.h>
#include <math.h>

#define BB 8
#define CIN 256
#define HW 4096
#define BHW 32768          // B*HW
#define COUT 256
#define KTOT 2304          // CIN*9
#define WS_N (BB*9*HW)     // 294912 floats per param array

// ws layout (floats):
//   0        sy   [WS_N]
//   WS_N     sx   [WS_N]
//   2*WS_N   m    [WS_N]
//   3*WS_N   w16s [294912 floats = 589824 bf16] (72 k-steps x 16KB contiguous)
#define WOFF2_OFF (4*WS_N)            // woff2 [256*9*28]
#define ACC_OFF   (WOFF2_OFF + 64512) // accum [27][BHW]
#define ATOMIC_NEED ((size_t)(ACC_OFF + 27*BHW) * 4)

typedef __bf16 bf16;
typedef __attribute__((ext_vector_type(8))) __bf16 bf16x8;
typedef __attribute__((ext_vector_type(4))) __bf16 bf16x4;
typedef __attribute__((ext_vector_type(4))) float f32x4;
struct __attribute__((packed, aligned(4))) f2x { float x, y; };

// ---------------- wprep: w_off [27][256*9] -> woff2 [(c*9+t)*28 + j] ----------------
__global__ __launch_bounds__(256) void wprep_kernel(
    const float* __restrict__ w_off, float* __restrict__ woff2)
{
  const int c = blockIdx.x;
  const int tid = threadIdx.x;
  if (tid < 252) {
    int t = tid / 28, j = tid % 28;
    float v = (j < 27) ? w_off[(size_t)j * KTOT + c * 9 + t] : 0.f;
    woff2[((size_t)c * 9 + t) * 28 + j] = v;
  }
}

// ---------------- offconv: NS-way c-split, atomicAdd accumulate ----------------
template<int NS>
__global__ __launch_bounds__(256) void offconv_atom_kernel(
    const float* __restrict__ x, const float* __restrict__ woff2,
    float* __restrict__ accum)
{
  const int tid = threadIdx.x;
  const int bs  = blockIdx.x;
  const int st  = bs & 15;
  const int b   = (bs >> 4) & 7;
  const int s   = bs >> 7;
  const int pos = st * 256 + tid;
  const int ho  = pos >> 6, wo = pos & 63;
  const int c0  = s * (CIN / NS), c1 = c0 + CIN / NS;

  int   toff[9];
  float tvf[9];
#pragma unroll
  for (int t = 0; t < 9; ++t) {
    int ky = t / 3, kx = t % 3;
    int yy = ho - 1 + ky, xx = wo - 1 + kx;
    bool ok = ((unsigned)yy < 64u) && ((unsigned)xx < 64u);
    toff[t] = (min(max(yy, 0), 63)) * 64 + min(max(xx, 0), 63);
    tvf[t]  = ok ? 1.f : 0.f;
  }

  float a[27];
#pragma unroll
  for (int j = 0; j < 27; ++j) a[j] = 0.f;

  const float* xb = x + (size_t)b * CIN * HW;
#pragma unroll 2
  for (int c = c0; c < c1; ++c) {
    const float* xc = xb + (size_t)c * HW;
    float xv[9];
#pragma unroll
    for (int t = 0; t < 9; ++t) xv[t] = xc[toff[t]] * tvf[t];
    const float4* wr4 = (const float4*)(woff2 + (size_t)c * 252);
#pragma unroll
    for (int t = 0; t < 9; ++t) {
      float4 wb[7];
#pragma unroll
      for (int q = 0; q < 7; ++q) wb[q] = wr4[t * 7 + q];
#pragma unroll
      for (int q = 0; q < 7; ++q) {
        int j0 = q * 4;
        a[j0 + 0] = fmaf(wb[q].x, xv[t], a[j0 + 0]);
        a[j0 + 1] = fmaf(wb[q].y, xv[t], a[j0 + 1]);
        a[j0 + 2] = fmaf(wb[q].z, xv[t], a[j0 + 2]);
        if (j0 + 3 < 27) a[j0 + 3] = fmaf(wb[q].w, xv[t], a[j0 + 3]);
      }
    }
  }

  const int bp = b * HW + pos;
#pragma unroll
  for (int j = 0; j < 27; ++j)
    atomicAdd(&accum[(size_t)j * BHW + bp], a[j]);
}

// fallback (no accum buffer): NS=1 direct write
__global__ __launch_bounds__(256) void offconv_direct_kernel(
    const float* __restrict__ x, const float* __restrict__ woff2,
    const float* __restrict__ b_off, float* __restrict__ ws)
{
  const int tid = threadIdx.x;
  const int bs  = blockIdx.x;
  const int st  = bs & 15;
  const int b   = bs >> 4;
  const int pos = st * 256 + tid;
  const int ho  = pos >> 6, wo = pos & 63;

  int   toff[9];
  float tvf[9];
#pragma unroll
  for (int t = 0; t < 9; ++t) {
    int ky = t / 3, kx = t % 3;
    int yy = ho - 1 + ky, xx = wo - 1 + kx;
    bool ok = ((unsigned)yy < 64u) && ((unsigned)xx < 64u);
    toff[t] = (min(max(yy, 0), 63)) * 64 + min(max(xx, 0), 63);
    tvf[t]  = ok ? 1.f : 0.f;
  }
  float a[27];
#pragma unroll
  for (int j = 0; j < 27; ++j) a[j] = 0.f;
  const float* xb = x + (size_t)b * CIN * HW;
#pragma unroll 2
  for (int c = 0; c < CIN; ++c) {
    const float* xc = xb + (size_t)c * HW;
    float xv[9];
#pragma unroll
    for (int t = 0; t < 9; ++t) xv[t] = xc[toff[t]] * tvf[t];
    const float4* wr4 = (const float4*)(woff2 + (size_t)c * 252);
#pragma unroll
    for (int t = 0; t < 9; ++t) {
      float4 wb[7];
#pragma unroll
      for (int q = 0; q < 7; ++q) wb[q] = wr4[t * 7 + q];
#pragma unroll
      for (int q = 0; q < 7; ++q) {
        int j0 = q * 4;
        a[j0 + 0] = fmaf(wb[q].x, xv[t], a[j0 + 0]);
        a[j0 + 1] = fmaf(wb[q].y, xv[t], a[j0 + 1]);
        a[j0 + 2] = fmaf(wb[q].z, xv[t], a[j0 + 2]);
        if (j0 + 3 < 27) a[j0 + 3] = fmaf(wb[q].w, xv[t], a[j0 + 3]);
      }
    }
  }
#pragma unroll
  for (int kk = 0; kk < 9; ++kk) {
    float syv = a[2 * kk]     + b_off[2 * kk]     + (float)(ho - 1 + kk / 3);
    float sxv = a[2 * kk + 1] + b_off[2 * kk + 1] + (float)(wo - 1 + kk % 3);
    float mv  = a[18 + kk]    + b_off[18 + kk];
    ws[(b * 9 + kk) * HW + pos]            = syv;
    ws[WS_N + (b * 9 + kk) * HW + pos]     = sxv;
    ws[2 * WS_N + (b * 9 + kk) * HW + pos] = 1.f / (1.f + expf(-mv));
  }
}

// ---------------- combine: accum + bias -> sy/sx/m ----------------
__global__ __launch_bounds__(256) void combine_kernel(
    const float* __restrict__ b_off, float* __restrict__ ws)
{
  int gid = blockIdx.x * 256 + threadIdx.x;
  int kk = gid >> 15, bp = gid & 32767;
  int b = bp >> 12, pos = bp & 4095;
  int ho = pos >> 6, wo = pos & 63;
  const float* acc = ws + ACC_OFF;
  int jy = 2 * kk, jx = 2 * kk + 1, jm = 18 + kk;
  float syv = acc[(size_t)jy * BHW + bp] + b_off[jy] + (float)(ho - 1 + kk / 3);
  float sxv = acc[(size_t)jx * BHW + bp] + b_off[jx] + (float)(wo - 1 + kk % 3);
  float mv  = acc[(size_t)jm * BHW + bp] + b_off[jm];
  ws[(b * 9 + kk) * HW + pos]            = syv;
  ws[WS_N + (b * 9 + kk) * HW + pos]     = sxv;
  ws[2 * WS_N + (b * 9 + kk) * HW + pos] = 1.f / (1.f + expf(-mv));
}

// ---------------- wconv: w_dcn -> bf16 staged tiles ----------------
// step ks = cblk*9+kk covers channels cblk*32..+31, tap kk.
// w16s[ks*8192 + (q*256 + co)*8 + j] = w_dcn[co][ (cblk*32+q*8+j)*9 + kk ]
__global__ __launch_bounds__(256) void wconv_kernel(
    const float* __restrict__ w, bf16* __restrict__ o)
{
  const int co = blockIdx.x;
  const int c  = threadIdx.x;
  const int cblk = c >> 5, cin = c & 31, q = cin >> 3, j = cin & 7;
#pragma unroll
  for (int kk = 0; kk < 9; ++kk)
    o[(size_t)(cblk * 9 + kk) * 8192 + (q * 256 + co) * 8 + j] =
      (bf16)w[(size_t)co * KTOT + c * 9 + kk];
}

// ---------------- dcn: bilinear gather + MFMA GEMM ----------------
// 1024 threads (16 waves, wave grid 4x4), tile 256co x 128pos, KSTEP 32, NK 72.
// A: global_load_lds dwordx4 from pre-staged contiguous tiles, double-buffered.
// B: reg-gather (issued 1 iter ahead) -> combine -> ds_write, double-buffered.
// Per iter: vmcnt(8) drains only the gl_lds; 8 B-gathers stay in flight across barrier.
#define NK 72

__device__ __forceinline__ void glds16(const bf16* g, bf16* l) {
  __builtin_amdgcn_global_load_lds(
      (const __attribute__((address_space(1))) void*)g,
      (__attribute__((address_space(3))) void*)l, 16, 0, 0);
}

__global__ __launch_bounds__(1024, 4) void dcn_mfma4_kernel(
    const float* __restrict__ x, const bf16* __restrict__ w16,
    const float* __restrict__ b_dcn, const float* __restrict__ ws,
    float* __restrict__ out)
{
  __shared__ bf16 A_lds[2][8192];      // [q][co][8k] granules, 16KB each
  __shared__ bf16 B_lds[2][1024];      // [q][p][8k] granules, 8KB each (128*32)
  __shared__ bf16 B_lds2[2][3072];     // rest of B (total 4096 elems/buf)
  __shared__ int   poff0[1152], poff1[1152];
  __shared__ float pa0s[1152], pa1s[1152], pw0s[1152], pw1s[1152];

  const int tid  = threadIdx.x;
  const int b    = blockIdx.x & 7;      // batch -> XCD
  const int pos0 = (blockIdx.x >> 3) * 128;

  // bilinear params per (kk, p)
  for (int t = tid; t < 1152; t += 1024) {
    int kk = t >> 7, p = t & 127;
    int pos = pos0 + p;
    float sy = ws[(b * 9 + kk) * HW + pos];
    float sx = ws[WS_N + (b * 9 + kk) * HW + pos];
    float m  = ws[2 * WS_N + (b * 9 + kk) * HW + pos];
    float y0f = floorf(sy), x0f = floorf(sx);
    int y0 = (int)y0f, x0 = (int)x0f;
    float wy = sy - y0f, wx = sx - x0f;
    int ix0 = min(max(x0, 0), 63), ix1 = min(max(x0 + 1, 0), 63);
    int bx  = min(max(x0, 0), 62);
    float vx0 = (x0 >= 0  && x0 <= 63) ? 1.f : 0.f;
    float vx1 = (x0 >= -1 && x0 <= 62) ? 1.f : 0.f;
    float wx0 = (1.f - wx) * vx0, wx1 = wx * vx1;
    float a0 = (ix0 == bx     ? wx0 : 0.f) + (ix1 == bx     ? wx1 : 0.f);
    float a1 = (ix0 == bx + 1 ? wx0 : 0.f) + (ix1 == bx + 1 ? wx1 : 0.f);
    int rb0 = min(max(y0, 0), 63), rb1 = min(max(y0 + 1, 0), 63);
    float vy0 = (y0 >= 0  && y0 <= 63) ? 1.f : 0.f;
    float vy1 = (y0 >= -1 && y0 <= 62) ? 1.f : 0.f;
    poff0[t] = rb0 * 64 + bx;
    poff1[t] = rb1 * 64 + bx;
    pa0s[t] = a0; pa1s[t] = a1;
    pw0s[t] = (1.f - wy) * vy0 * m;
    pw1s[t] = wy * vy1 * m;
  }
  __syncthreads();

  const int lane = tid & 63, wid = tid >> 6;
  const int wr = wid >> 2, wc = wid & 3;     // 4x4 wave grid: 64co x 32pos each
  const int lm = lane & 15, lk = lane >> 4;
  const int gp = tid & 127, gg = tid >> 7;   // gather: pos p, k-quad gg in [0,8)

  f32x4 acc[4][2];
#pragma unroll
  for (int a = 0; a < 4; ++a)
#pragma unroll
    for (int c = 0; c < 2; ++c)
      acc[a][c] = (f32x4){0.f, 0.f, 0.f, 0.f};

  const float* xb = x + (size_t)b * CIN * HW;
  // B write slot (elements): granule (gg>>1)*128 + gp, half (gg&1)
  const int bwoff = (((gg >> 1) * 128 + gp) << 3) + ((gg & 1) << 2);

  int   o0, o1;
  float pa0, pa1, pw0, pw1;
  f2x r0[4], r1[4];

  // ---- prologue: step 0
  o0 = poff0[gp]; o1 = poff1[gp];
  pa0 = pa0s[gp]; pa1 = pa1s[gp]; pw0 = pw0s[gp]; pw1 = pw1s[gp];
  {
    const float* pc = xb + (size_t)(gg * 4) * HW;
#pragma unroll
    for (int e = 0; e < 4; ++e) {
      r0[e] = *(const f2x*)(pc + o0);
      r1[e] = *(const f2x*)(pc + o1);
      pc += HW;
    }
  }
  glds16(w16 + tid * 8, &A_lds[0][0] + wid * 512);
  {
    bf16x4 vv;
#pragma unroll
    for (int e = 0; e < 4; ++e) {
      float v = pw0 * fmaf(pa0, r0[e].x, pa1 * r0[e].y)
              + pw1 * fmaf(pa0, r1[e].x, pa1 * r1[e].y);
      vv[e] = (bf16)v;
    }
    bf16* bbuf = (bwoff < 1024) ? &B_lds[0][bwoff] : &B_lds2[0][bwoff - 1024];
    *(bf16x4*)bbuf = vv;
  }
  // issue step-1 gathers (tap 1, cblk 0)
  o0 = poff0[128 + gp]; o1 = poff1[128 + gp];
  pa0 = pa0s[128 + gp]; pa1 = pa1s[128 + gp]; pw0 = pw0s[128 + gp]; pw1 = pw1s[128 + gp];
  {
    const float* pc = xb + (size_t)(gg * 4) * HW;
#pragma unroll
    for (int e = 0; e < 4; ++e) {
      r0[e] = *(const f2x*)(pc + o0);
      r1[e] = *(const f2x*)(pc + o1);
      pc += HW;
    }
  }
  asm volatile("s_waitcnt vmcnt(8)" ::: "memory");
  asm volatile("s_waitcnt lgkmcnt(0)" ::: "memory");
  __builtin_amdgcn_sched_barrier(0);
  __builtin_amdgcn_s_barrier();

  // ---- main loop
  int t1 = 1, t2 = 2, cb2 = 0;
  for (int i = 0; i < NK - 1; ++i) {
    const int ri = i & 1, wi = ri ^ 1;

    // stage A(i+1) direct to LDS (coalesced 16KB tile)
    glds16(w16 + (size_t)(i + 1) * 8192 + tid * 8, &A_lds[wi][0] + wid * 512);

    // combine B(i+1) from regs (params/regs loaded last iter), write LDS
    {
      bf16x4 vv;
#pragma unroll
      for (int e = 0; e < 4; ++e) {
        float v = pw0 * fmaf(pa0, r0[e].x, pa1 * r0[e].y)
                + pw1 * fmaf(pa0, r1[e].x, pa1 * r1[e].y);
        vv[e] = (bf16)v;
      }
      bf16* bbuf = (bwoff < 1024) ? &B_lds[wi][bwoff] : &B_lds2[wi][bwoff - 1024];
      *(bf16x4*)bbuf = vv;
    }
    // issue gathers for step i+2 (clamped)
    {
      int pb = t2 * 128 + gp;
      o0 = poff0[pb]; o1 = poff1[pb];
      pa0 = pa0s[pb]; pa1 = pa1s[pb]; pw0 = pw0s[pb]; pw1 = pw1s[pb];
      const float* pc = xb + (size_t)(cb2 + gg * 4) * HW;
#pragma unroll
      for (int e = 0; e < 4; ++e) {
        r0[e] = *(const f2x*)(pc + o0);
        r1[e] = *(const f2x*)(pc + o1);
        pc += HW;
      }
    }
    // fragments (step i) + 8 MFMA
    {
      const bf16* Ab = &A_lds[ri][0];
      bf16x8 af0 = *(const bf16x8*)(Ab + ((lk * 256 + wr * 64 +  0 + lm) << 3));
      bf16x8 af1 = *(const bf16x8*)(Ab + ((lk * 256 + wr * 64 + 16 + lm) << 3));
      bf16x8 af2 = *(const bf16x8*)(Ab + ((lk * 256 + wr * 64 + 32 + lm) << 3));
      bf16x8 af3 = *(const bf16x8*)(Ab + ((lk * 256 + wr * 64 + 48 + lm) << 3));
      int bidx0 = (lk * 128 + wc * 32 +  0 + lm) << 3;
      int bidx1 = (lk * 128 + wc * 32 + 16 + lm) << 3;
      bf16x8 bf0 = *(const bf16x8*)((bidx0 < 1024) ? &B_lds[ri][bidx0] : &B_lds2[ri][bidx0 - 1024]);
      bf16x8 bf1 = *(const bf16x8*)((bidx1 < 1024) ? &B_lds[ri][bidx1] : &B_lds2[ri][bidx1 - 1024]);
      acc[0][0] = __builtin_amdgcn_mfma_f32_16x16x32_bf16(af0, bf0, acc[0][0], 0, 0, 0);
      acc[0][1] = __builtin_amdgcn_mfma_f32_16x16x32_bf16(af0, bf1, acc[0][1], 0, 0, 0);
      acc[1][0] = __builtin_amdgcn_mfma_f32_16x16x32_bf16(af1, bf0, acc[1][0], 0, 0, 0);
      acc[1][1] = __builtin_amdgcn_mfma_f32_16x16x32_bf16(af1, bf1, acc[1][1], 0, 0, 0);
      acc[2][0] = __builtin_amdgcn_mfma_f32_16x16x32_bf16(af2, bf0, acc[2][0], 0, 0, 0);
      acc[2][1] = __builtin_amdgcn_mfma_f32_16x16x32_bf16(af2, bf1, acc[2][1], 0, 0, 0);
      acc[3][0] = __builtin_amdgcn_mfma_f32_16x16x32_bf16(af3, bf0, acc[3][0], 0, 0, 0);
      acc[3][1] = __builtin_amdgcn_mfma_f32_16x16x32_bf16(af3, bf1, acc[3][1], 0, 0, 0);
    }
    asm volatile("s_waitcnt vmcnt(8)" ::: "memory");   // drain gl_lds only
    asm volatile("s_waitcnt lgkmcnt(0)" ::: "memory"); // drain ds writes/reads
    __builtin_amdgcn_sched_barrier(0);
    __builtin_amdgcn_s_barrier();

    ++t1; if (t1 == 9) t1 = 0;
    ++t2; if (t2 == 9) { t2 = 0; cb2 += 32; }
    if (cb2 == 256) { cb2 = 224; t2 = 8; }
  }

  // ---- final step NK-1
  {
    const int ri = (NK - 1) & 1;
    const bf16* Ab = &A_lds[ri][0];
    bf16x8 af0 = *(const bf16x8*)(Ab + ((lk * 256 + wr * 64 +  0 + lm) << 3));
    bf16x8 af1 = *(const bf16x8*)(Ab + ((lk * 256 + wr * 64 + 16 + lm) << 3));
    bf16x8 af2 = *(const bf16x8*)(Ab + ((lk * 256 + wr * 64 + 32 + lm) << 3));
    bf16x8 af3 = *(const bf16x8*)(Ab + ((lk * 256 + wr * 64 + 48 + lm) << 3));
    int bidx0 = (lk * 128 + wc * 32 +  0 + lm) << 3;
    int bidx1 = (lk * 128 + wc * 32 + 16 + lm) << 3;
    bf16x8 bf0 = *(const bf16x8*)((bidx0 < 1024) ? &B_lds[ri][bidx0] : &B_lds2[ri][bidx0 - 1024]);
    bf16x8 bf1 = *(const bf16x8*)((bidx1 < 1024) ? &B_lds[ri][bidx1] : &B_lds2[ri][bidx1 - 1024]);
    acc[0][0] = __builtin_amdgcn_mfma_f32_16x16x32_bf16(af0, bf0, acc[0][0], 0, 0, 0);
    acc[0][1] = __builtin_amdgcn_mfma_f32_16x16x32_bf16(af0, bf1, acc[0][1], 0, 0, 0);
    acc[1][0] = __builtin_amdgcn_mfma_f32_16x16x32_bf16(af1, bf0, acc[1][0], 0, 0, 0);
    acc[1][1] = __builtin_amdgcn_mfma_f32_16x16x32_bf16(af1, bf1, acc[1][1], 0, 0, 0);
    acc[2][0] = __builtin_amdgcn_mfma_f32_16x16x32_bf16(af2, bf0, acc[2][0], 0, 0, 0);
    acc[2][1] = __builtin_amdgcn_mfma_f32_16x16x32_bf16(af2, bf1, acc[2][1], 0, 0, 0);
    acc[3][0] = __builtin_amdgcn_mfma_f32_16x16x32_bf16(af3, bf0, acc[3][0], 0, 0, 0);
    acc[3][1] = __builtin_amdgcn_mfma_f32_16x16x32_bf16(af3, bf1, acc[3][1], 0, 0, 0);
  }

  // ---- epilogue: bias + store (C/D: col=lane&15, row=(lane>>4)*4+reg)
  const int pbase = pos0 + wc * 32;
#pragma unroll
  for (int fr = 0; fr < 4; ++fr) {
#pragma unroll
    for (int r = 0; r < 4; ++r) {
      int co = wr * 64 + fr * 16 + lk * 4 + r;
      float bias = b_dcn[co];
      float* orow = out + ((size_t)b * COUT + co) * HW + pbase;
      orow[lm]      = acc[fr][0][r] + bias;
      orow[16 + lm] = acc[fr][1][r] + bias;
    }
  }
}

extern "C" void kernel_launch(void* const* d_in, const int* in_sizes, int n_in,
                              void* d_out, int out_size, void* d_ws, size_t ws_size,
                              hipStream_t stream) {
  const float* x     = (const float*)d_in[0];
  const float* w_off = (const float*)d_in[1];
  const float* b_off = (const float*)d_in[2];
  const float* w_dcn = (const float*)d_in[3];
  const float* b_dcn = (const float*)d_in[4];
  float* out = (float*)d_out;
  float* ws  = (float*)d_ws;
  bf16* w16  = (bf16*)(ws + 3 * WS_N);
  float* woff2 = ws + WOFF2_OFF;

  wprep_kernel<<<256, 256, 0, stream>>>(w_off, woff2);
  if (ws_size >= ATOMIC_NEED) {
    hipMemsetAsync(ws + ACC_OFF, 0, (size_t)27 * BHW * 4, stream);
    offconv_atom_kernel<8><<<8 * BB * 16, 256, 0, stream>>>(x, woff2, ws + ACC_OFF);
    combine_kernel<<<(9 * BHW) / 256, 256, 0, stream>>>(b_off, ws);
  } else {
    offconv_direct_kernel<<<BB * 16, 256, 0, stream>>>(x, woff2, b_off, ws);
  }
  wconv_kernel<<<COUT, 256, 0, stream>>>(w_dcn, w16);
  dcn_mfma4_kernel<<<BB * (HW / 128), 1024, 0, stream>>>(x, w16, b_dcn, ws, out);
}